// Round 16
// baseline (1316.159 us; speedup 1.0000x reference)
//
#include <hip/hip_runtime.h>
#include <stdint.h>

#define NSEQ 641
#define BATCH 16
#define MROWS (BATCH * NSEQ)   // 10256
#define HID 512
#define FFD 2048
#define NHEAD 8
#define HDIM 64
#define NLAYER 6
#define VOCAB 1024
#define KPAD 704               // padded key length for vT rows (mult of 64)

typedef __bf16 bf16x8 __attribute__((ext_vector_type(8)));
typedef float  f32x4  __attribute__((ext_vector_type(4)));
typedef int    i32x4  __attribute__((ext_vector_type(4)));
typedef short  s16x8  __attribute__((ext_vector_type(8)));
typedef short  s16x4  __attribute__((ext_vector_type(4)));

#define EXP_C 0.18033688011112042f   // 0.125 * log2(e)

// XOR swizzle, 128B row pitch (attn K/V/P tiles). Involution.
__device__ __forceinline__ uint32_t swz(uint32_t b) { return b ^ (((b >> 7) & 7u) << 4); }
// XOR swizzle, 64B row pitch (gemm BK=32 tiles). Involution.
__device__ __forceinline__ uint32_t swz32(uint32_t b) { return b ^ (((b >> 7) & 3u) << 4); }

// XCD-chunked bijective block swizzle.
__device__ __forceinline__ int xcd_swz(int bid, int nwg) {
  int x = bid & 7, j = bid >> 3;
  int q = nwg >> 3, r = nwg & 7;
  return x * q + (x < r ? x : r) + j;
}

__device__ __forceinline__ unsigned short f2bf(float f) {
  uint32_t u = __builtin_bit_cast(uint32_t, f);
  u += 0x7FFFu + ((u >> 16) & 1u);
  return (unsigned short)(u >> 16);
}

__device__ __forceinline__ float bf2f(unsigned short u) {
  uint32_t t = ((uint32_t)u) << 16;
  return __builtin_bit_cast(float, t);
}

__device__ __forceinline__ void gload16(const void* g, void* l) {
  __builtin_amdgcn_global_load_lds(
      (const __attribute__((address_space(1))) uint32_t*)g,
      (__attribute__((address_space(3))) uint32_t*)l, 16, 0, 0);
}

__device__ __forceinline__ bf16x8 ld_lds16(const void* p) {
  return __builtin_bit_cast(bf16x8, *(const i32x4*)p);
}

// ---------------------------------------------------------------------------
// f32 -> bf16 conversion (weights)
// ---------------------------------------------------------------------------
__global__ void cvt_kernel(const float* __restrict__ in,
                           unsigned short* __restrict__ out, int n) {
  int i = (blockIdx.x * 256 + threadIdx.x) * 4;
  if (i >= n) return;
  f32x4 v = *(const f32x4*)(in + i);
  s16x4 o;
  o[0] = (short)f2bf(v[0]); o[1] = (short)f2bf(v[1]);
  o[2] = (short)f2bf(v[2]); o[3] = (short)f2bf(v[3]);
  *(s16x4*)(out + i) = o;
}

// ---------------------------------------------------------------------------
// Embedding: xb = bf16(emb[tok] + pe[n])
// ---------------------------------------------------------------------------
__global__ void embed_kernel(const int* __restrict__ tok,
                             const float* __restrict__ emb,
                             const float* __restrict__ pe,
                             unsigned short* __restrict__ xb) {
  int m = blockIdx.x;
  int n = m % NSEQ;
  int t = tok[m];
  int h = threadIdx.x * 4;
  f32x4 e = *(const f32x4*)(emb + (size_t)t * HID + h);
  f32x4 p = *(const f32x4*)(pe + (size_t)n * HID + h);
  f32x4 v = e + p;
  s16x4 o;
  o[0] = (short)f2bf(v[0]); o[1] = (short)f2bf(v[1]);
  o[2] = (short)f2bf(v[2]); o[3] = (short)f2bf(v[3]);
  *(s16x4*)(xb + (size_t)m * HID + h) = o;
}

// ---------------------------------------------------------------------------
// LayerNorm over H=512, bf16 in -> bf16 out, one wave per row (f32 math).
// ---------------------------------------------------------------------------
__global__ __launch_bounds__(256) void ln_kernel(
    const unsigned short* __restrict__ in, const float* __restrict__ gg,
    const float* __restrict__ bb, unsigned short* __restrict__ out, int rows) {
  int row = blockIdx.x * 4 + (threadIdx.x >> 6);
  if (row >= rows) return;
  int lane = threadIdx.x & 63;
  s16x8 raw = *(const s16x8*)(in + (size_t)row * HID + lane * 8);
  float a[8];
#pragma unroll
  for (int j = 0; j < 8; ++j) a[j] = bf2f((unsigned short)raw[j]);
  float s = a[0] + a[1] + a[2] + a[3] + a[4] + a[5] + a[6] + a[7];
#pragma unroll
  for (int o = 32; o; o >>= 1) s += __shfl_xor(s, o);
  float mean = s * (1.0f / HID);
  float vs = 0.f;
#pragma unroll
  for (int j = 0; j < 8; ++j) { float d = a[j] - mean; vs += d * d; }
#pragma unroll
  for (int o = 32; o; o >>= 1) vs += __shfl_xor(vs, o);
  float rstd = rsqrtf(vs * (1.0f / HID) + 1e-5f);
  f32x4 g0 = *(const f32x4*)(gg + lane * 8);
  f32x4 g1 = *(const f32x4*)(gg + lane * 8 + 4);
  f32x4 b0 = *(const f32x4*)(bb + lane * 8);
  f32x4 b1 = *(const f32x4*)(bb + lane * 8 + 4);
  s16x8 ob;
#pragma unroll
  for (int j = 0; j < 4; ++j) {
    ob[j]     = (short)f2bf((a[j]     - mean) * rstd * g0[j] + b0[j]);
    ob[j + 4] = (short)f2bf((a[j + 4] - mean) * rstd * g1[j] + b1[j]);
  }
  *(s16x8*)(out + (size_t)row * HID + lane * 8) = ob;
}

// ---------------------------------------------------------------------------
// GEMM epilogue selector
// ---------------------------------------------------------------------------
enum { EPI_QKV = 0, EPI_GELU = 1, EPI_RESID = 2, EPI_F32OUT = 3 };

template <int EPI>
__device__ __forceinline__ void gemm_epilogue_elem(
    float v, int m, int c, int N,
    const unsigned short* resid, void* out0, void* out1, void* out2) {
  if (EPI == EPI_QKV) {
    int bbq = m / NSEQ, nn = m - bbq * NSEQ;
    int which = c >> 9, hh = (c >> 6) & 7, d = c & 63;
    if (which == 2) {
      // V written directly in transposed layout vT[bh][d][KPAD]
      ((unsigned short*)out2)[(((size_t)bbq * NHEAD + hh) * HDIM + d) * KPAD + nn] = f2bf(v);
    } else {
      unsigned short* dst = which == 0 ? (unsigned short*)out0 : (unsigned short*)out1;
      dst[(((size_t)bbq * NHEAD + hh) * NSEQ + nn) * HDIM + d] = f2bf(v);
    }
  } else if (EPI == EPI_GELU) {
    v = 0.5f * v * (1.0f + erff(v * 0.70710678118654752f));
    ((unsigned short*)out0)[(size_t)m * N + c] = f2bf(v);
  } else if (EPI == EPI_RESID) {
    ((unsigned short*)out0)[(size_t)m * N + c] =
        f2bf(v + bf2f(resid[(size_t)m * N + c]));
  } else {
    ((float*)out0)[(size_t)m * N + c] = v;
  }
}

// ---------------------------------------------------------------------------
// GEMM (4-wave): BM x 128 tile, BK=32, 3-deep pipeline, counted vmcnt.
// ---------------------------------------------------------------------------
template <int EPI, int BM>
__global__ __launch_bounds__(256, 3) void gemm_bt(
    const unsigned short* __restrict__ A, const unsigned short* __restrict__ W,
    const float* __restrict__ bias, const unsigned short* __restrict__ resid,
    void* __restrict__ out0, void* __restrict__ out1, void* __restrict__ out2,
    int M, int N, int K) {
  constexpr int ASZ = BM * 64;
  constexpr int BUF = ASZ + 8192;
  constexpr int MI = BM >> 5;
  constexpr int WROWS = BM >> 1;
  constexpr int ALOADS = ASZ / 4096;
  __shared__ char sm[3][BUF];
  const int tid = threadIdx.x, lane = tid & 63, wid = tid >> 6;
  const int wr = wid >> 1, wc = wid & 1;
  const int lg = lane >> 4, lc = lane & 15;

  const int nx = N >> 7;
  const int logical = xcd_swz(blockIdx.x, gridDim.x);
  const int m0 = (logical / nx) * BM, n0 = (logical % nx) * 128;

  f32x4 acc[MI][4] = {};

  auto stage = [&](int kt, char* dst) {
#pragma unroll
    for (int i = 0; i < ALOADS; ++i) {
      uint32_t P = (uint32_t)tid * 16 + i * 4096;
      uint32_t L = swz32(P);
      int row = (int)(L >> 6);
      uint32_t kb = L & 63u;
      int ma = m0 + row; if (ma >= M) ma = M - 1;
      gload16((const char*)A + ((size_t)ma * K + kt) * 2 + kb, dst + P);
    }
#pragma unroll
    for (int i = 0; i < 2; ++i) {
      uint32_t P = (uint32_t)tid * 16 + i * 4096;
      uint32_t L = swz32(P);
      int row = (int)(L >> 6);
      uint32_t kb = L & 63u;
      gload16((const char*)W + ((size_t)(n0 + row) * K + kt) * 2 + kb,
              dst + ASZ + P);
    }
  };

  const int nk = K >> 5;
  stage(0, sm[0]);
  stage(32, sm[1]);

  int bc = 0;
  for (int t = 0; t < nk; ++t) {
    if (t + 1 < nk) {
      if constexpr (ALOADS == 2) asm volatile("s_waitcnt vmcnt(4)" ::: "memory");
      else                       asm volatile("s_waitcnt vmcnt(3)" ::: "memory");
    } else {
      asm volatile("s_waitcnt vmcnt(0)" ::: "memory");
    }
    __builtin_amdgcn_sched_barrier(0);
    __builtin_amdgcn_s_barrier();
    __builtin_amdgcn_sched_barrier(0);
    if (t + 2 < nk) {
      int b2 = bc + 2; if (b2 >= 3) b2 -= 3;
      stage((t + 2) << 5, sm[b2]);
    }
    const char* buf = sm[bc];
    bf16x8 af[MI], bfr[4];
#pragma unroll
    for (int mi = 0; mi < MI; ++mi) {
      int row = wr * WROWS + mi * 16 + lc;
      af[mi] = ld_lds16(buf + swz32((uint32_t)row * 64 + (lg << 4)));
    }
#pragma unroll
    for (int ni = 0; ni < 4; ++ni) {
      int row = wc * 64 + ni * 16 + lc;
      bfr[ni] = ld_lds16(buf + ASZ + swz32((uint32_t)row * 64 + (lg << 4)));
    }
#pragma unroll
    for (int mi = 0; mi < MI; ++mi)
#pragma unroll
      for (int ni = 0; ni < 4; ++ni)
        acc[mi][ni] = __builtin_amdgcn_mfma_f32_16x16x32_bf16(af[mi], bfr[ni], acc[mi][ni], 0, 0, 0);
    asm volatile("s_waitcnt lgkmcnt(0)" ::: "memory");
    __builtin_amdgcn_sched_barrier(0);
    if (++bc == 3) bc = 0;
  }

#pragma unroll
  for (int mi = 0; mi < MI; ++mi) {
#pragma unroll
    for (int g = 0; g < 4; ++g) {
      int m = m0 + wr * WROWS + mi * 16 + lg * 4 + g;
      if (m >= M) continue;
#pragma unroll
      for (int ni = 0; ni < 4; ++ni) {
        int c = n0 + wc * 64 + ni * 16 + lc;
        float v = acc[mi][ni][g] + bias[c];
        gemm_epilogue_elem<EPI>(v, m, c, N, resid, out0, out1, out2);
      }
    }
  }
}

// ---------------------------------------------------------------------------
// GEMM (8-wave): 256x128 tile, 512 threads, BK=32, 2-buffer depth-1.
// Kept ONLY for QKV (the measured R12 win on its 12-wide grid).
// ---------------------------------------------------------------------------
template <int EPI>
__global__ __launch_bounds__(512, 3) void gemm_bt8(
    const unsigned short* __restrict__ A, const unsigned short* __restrict__ W,
    const float* __restrict__ bias, const unsigned short* __restrict__ resid,
    void* __restrict__ out0, void* __restrict__ out1, void* __restrict__ out2,
    int M, int N, int K) {
  __shared__ char sm[2][24576];   // A 256x32 bf16 =16KB | B 128x32 bf16 =8KB
  const int tid = threadIdx.x, lane = tid & 63, wid = tid >> 6;
  const int wr = wid >> 1, wc = wid & 1;        // 4 x 2 waves
  const int lg = lane >> 4, lc = lane & 15;

  const int nx = N >> 7;
  const int logical = xcd_swz(blockIdx.x, gridDim.x);
  const int m0 = (logical / nx) * 256, n0 = (logical % nx) * 128;

  f32x4 acc[4][4] = {};

  auto stage = [&](int kt, char* dst) {
#pragma unroll
    for (int i = 0; i < 2; ++i) {
      uint32_t P = (uint32_t)tid * 16 + i * 8192;
      uint32_t L = swz32(P);
      int row = (int)(L >> 6);
      uint32_t kb = L & 63u;
      int ma = m0 + row; if (ma >= M) ma = M - 1;
      gload16((const char*)A + ((size_t)ma * K + kt) * 2 + kb, dst + P);
    }
    {
      uint32_t P = (uint32_t)tid * 16;
      uint32_t L = swz32(P);
      int row = (int)(L >> 6);
      uint32_t kb = L & 63u;
      gload16((const char*)W + ((size_t)(n0 + row) * K + kt) * 2 + kb,
              dst + 16384 + P);
    }
  };

  const int nk = K >> 5;
  stage(0, sm[0]);

  for (int t = 0; t < nk; ++t) {
    asm volatile("s_waitcnt vmcnt(0)" ::: "memory");
    __builtin_amdgcn_sched_barrier(0);
    __builtin_amdgcn_s_barrier();
    __builtin_amdgcn_sched_barrier(0);
    if (t + 1 < nk) stage((t + 1) << 5, sm[(t + 1) & 1]);
    const char* buf = sm[t & 1];
    bf16x8 af[4], bfr[4];
#pragma unroll
    for (int mi = 0; mi < 4; ++mi) {
      int row = wr * 64 + mi * 16 + lc;
      af[mi] = ld_lds16(buf + swz32((uint32_t)row * 64 + (lg << 4)));
    }
#pragma unroll
    for (int ni = 0; ni < 4; ++ni) {
      int row = wc * 64 + ni * 16 + lc;
      bfr[ni] = ld_lds16(buf + 16384 + swz32((uint32_t)row * 64 + (lg << 4)));
    }
#pragma unroll
    for (int mi = 0; mi < 4; ++mi)
#pragma unroll
      for (int ni = 0; ni < 4; ++ni)
        acc[mi][ni] = __builtin_amdgcn_mfma_f32_16x16x32_bf16(af[mi], bfr[ni], acc[mi][ni], 0, 0, 0);
    asm volatile("s_waitcnt lgkmcnt(0)" ::: "memory");
    __builtin_amdgcn_sched_barrier(0);
  }

#pragma unroll
  for (int mi = 0; mi < 4; ++mi) {
#pragma unroll
    for (int g = 0; g < 4; ++g) {
      int m = m0 + wr * 64 + mi * 16 + lg * 4 + g;
      if (m >= M) continue;
#pragma unroll
      for (int ni = 0; ni < 4; ++ni) {
        int c = n0 + wc * 64 + ni * 16 + lc;
        float v = acc[mi][ni][g] + bias[c];
        gemm_epilogue_elem<EPI>(v, m, c, N, resid, out0, out1, out2);
      }
    }
  }
}

// ---------------------------------------------------------------------------
// Flash attention (R15 paths): 64-row q-tiles, no-max softmax, gload16
// double-buffered K/V staging, 40KB LDS -> 4 blocks/CU, provable
// lookahead-tile skip (nkt = qt+1 except qt in {1,6}).
// ---------------------------------------------------------------------------
__global__ __launch_bounds__(256, 4) void attn_kernel(
    const unsigned short* __restrict__ Q, const unsigned short* __restrict__ Kb,
    const unsigned short* __restrict__ vT, unsigned short* __restrict__ O) {
  const int logical = xcd_swz(blockIdx.x, gridDim.x);
  const int qt = logical % 11, bh = logical / 11;
  const int b = bh >> 3, h = bh & 7;
  const int q0 = qt * 64;
  const int tid = threadIdx.x, lane = tid & 63, w = tid >> 6;
  const int lg = lane >> 4, lc = lane & 15;
  __shared__ char smem[40960];  // sK[2][8192] | sV[2][8192] | sP[4][2048]

  const size_t base = (size_t)bh * (NSEQ * HDIM);
  const size_t baseT = (size_t)bh * (HDIM * KPAD);

  bf16x8 qf[2];
  {
    int qr = q0 + w * 16 + lc;
    if (qr > NSEQ - 1) qr = NSEQ - 1;
#pragma unroll
    for (int kk = 0; kk < 2; ++kk)
      qf[kk] = __builtin_bit_cast(
          bf16x8, *(const i32x4*)(Q + base + (size_t)qr * HDIM + kk * 32 + (lg << 3)));
  }

  f32x4 acc[4] = {};
  float lsum[4] = {0.f, 0.f, 0.f, 0.f};
  const int qrow_base = q0 + w * 16 + (lg << 2);

  int nkt = qt + 1 + ((qt == 1 || qt == 6) ? 1 : 0);
  if (nkt > 11) nkt = 11;

  auto stage = [&](int kt, int bufi) {
    const int k0 = kt * 64;
#pragma unroll
    for (int i = 0; i < 2; ++i) {
      uint32_t P = w * 2048 + i * 1024 + lane * 16;
      uint32_t L = swz(P);
      int row = (int)(L >> 7);
      uint32_t kbyte = L & 127u;
      int kr = k0 + row; if (kr > NSEQ - 1) kr = NSEQ - 1;
      gload16((const char*)(Kb + base + (size_t)kr * HDIM) + kbyte,
              smem + bufi * 8192 + w * 2048 + i * 1024);
      gload16((const char*)(vT + baseT + (size_t)row * KPAD + k0) + kbyte,
              smem + 16384 + bufi * 8192 + w * 2048 + i * 1024);
    }
  };

  stage(0, 0);
  __syncthreads();

  for (int kt = 0; kt < nkt; ++kt) {
    if (kt + 1 < nkt) stage(kt + 1, (kt + 1) & 1);
    const char* bK = smem + (kt & 1) * 8192;
    const char* bV = smem + 16384 + (kt & 1) * 8192;
    char* sPw = smem + 32768 + w * 2048;
    const int k0 = kt * 64;

    f32x4 s[4] = {};
#pragma unroll
    for (int nt = 0; nt < 4; ++nt) {
#pragma unroll
      for (int kk = 0; kk < 2; ++kk) {
        int row = nt * 16 + lc;
        bf16x8 kf = ld_lds16(bK + swz((uint32_t)row * 128 + kk * 64 + (lg << 4)));
        s[nt] = __builtin_amdgcn_mfma_f32_16x16x32_bf16(qf[kk], kf, s[nt], 0, 0, 0);
      }
    }

    if (kt < qt) {
#pragma unroll
      for (int g = 0; g < 4; ++g)
#pragma unroll
        for (int nt = 0; nt < 4; ++nt) {
          float p = exp2f(s[nt][g] * EXP_C);
          s[nt][g] = p;
          lsum[g] += p;
        }
    } else if (kt == qt) {
#pragma unroll
      for (int g = 0; g < 4; ++g) {
        int q = qrow_base + g;
        int pp = q / 40;
        int lo = pp * 40 + 1, hi = pp * 40 + 8;
#pragma unroll
        for (int nt = 0; nt < 4; ++nt) {
          int k = k0 + nt * 16 + lc;
          bool ok = ((k <= q) || (k >= lo && k <= hi)) && (k < NSEQ);
          float p = ok ? exp2f(s[nt][g] * EXP_C) : 0.f;
          s[nt][g] = p;
          lsum[g] += p;
        }
      }
    } else {
#pragma unroll
      for (int g = 0; g < 4; ++g) {
        int q = qrow_base + g;
        int pp = q / 40;
        int lo = pp * 40 + 1, hi = pp * 40 + 8;
#pragma unroll
        for (int nt = 0; nt < 4; ++nt) {
          int k = k0 + nt * 16 + lc;
          bool ok = (k >= lo && k <= hi) && (k < NSEQ);
          float p = ok ? exp2f(s[nt][g] * EXP_C) : 0.f;
          s[nt][g] = p;
          lsum[g] += p;
        }
      }
    }

#pragma unroll
    for (int g = 0; g < 4; ++g) {
      int row = (lg << 2) + g;
#pragma unroll
      for (int nt = 0; nt < 4; ++nt) {
        int col = nt * 16 + lc;
        *(short*)(sPw + swz((uint32_t)row * 128 + col * 2)) = (short)f2bf(s[nt][g]);
      }
    }
#pragma unroll
    for (int kk = 0; kk < 2; ++kk) {
      bf16x8 pa = ld_lds16(sPw + swz((uint32_t)lc * 128 + kk * 64 + (lg << 4)));
#pragma unroll
      for (int nt = 0; nt < 4; ++nt) {
        int rowv = nt * 16 + lc;
        bf16x8 vf = ld_lds16(bV + swz((uint32_t)rowv * 128 + kk * 64 + (lg << 4)));
        acc[nt] = __builtin_amdgcn_mfma_f32_16x16x32_bf16(pa, vf, acc[nt], 0, 0, 0);
      }
    }
    __syncthreads();
  }

#pragma unroll
  for (int o = 1; o < 16; o <<= 1)
#pragma unroll
    for (int g = 0; g < 4; ++g) lsum[g] += __shfl_xor(lsum[g], o);

#pragma unroll
  for (int g = 0; g < 4; ++g) {
    int q = qrow_base + g;
    if (q >= NSEQ) continue;
    float inv = 1.0f / lsum[g];
#pragma unroll
    for (int nt = 0; nt < 4; ++nt) {
      int d = nt * 16 + lc;
      O[((size_t)b * NSEQ + q) * HID + h * HDIM + d] = f2bf(acc[nt][g] * inv);
    }
  }
}

// ---------------------------------------------------------------------------
extern "C" void kernel_launch(void* const* d_in, const int* in_sizes, int n_in,
                              void* d_out, int out_size, void* d_ws, size_t ws_size,
                              hipStream_t stream) {
  const int*   tok   = (const int*)d_in[0];
  const float* pe    = (const float*)d_in[2];
  const float* emb   = (const float*)d_in[3];
  const float* qkv_w = (const float*)d_in[4];
  const float* qkv_b = (const float*)d_in[5];
  const float* out_w = (const float*)d_in[6];
  const float* out_b = (const float*)d_in[7];
  const float* ln1_g = (const float*)d_in[8];
  const float* ln1_b = (const float*)d_in[9];
  const float* fc1_w = (const float*)d_in[10];
  const float* fc1_b = (const float*)d_in[11];
  const float* fc2_w = (const float*)d_in[12];
  const float* fc2_b = (const float*)d_in[13];
  const float* ln2_g = (const float*)d_in[14];
  const float* ln2_b = (const float*)d_in[15];
  const float* lnf_g = (const float*)d_in[16];
  const float* lnf_b = (const float*)d_in[17];
  const float* dep_w = (const float*)d_in[18];
  const float* dep_b = (const float*)d_in[19];

  const size_t SZ_QKV = (size_t)1536 * 512;
  const size_t SZ_OUT = (size_t)512 * 512;
  const size_t SZ_FC1 = (size_t)2048 * 512;
  const size_t SZ_FC2 = (size_t)512 * 2048;
  const size_t SZ_DEP = (size_t)VOCAB * 512;

  char* w = (char*)d_ws;
  unsigned short* xb = (unsigned short*)w; w += (size_t)MROWS * HID * 2;
  unsigned short* sb = (unsigned short*)w; w += (size_t)MROWS * HID * 2;
  unsigned short* qb = (unsigned short*)w; w += (size_t)BATCH * NHEAD * NSEQ * HDIM * 2;
  unsigned short* kb = (unsigned short*)w; w += (size_t)BATCH * NHEAD * NSEQ * HDIM * 2;
  /* spacer (old vb region; keeps mid's 42MB aliasing span) */
  w += (size_t)BATCH * NHEAD * NSEQ * HDIM * 2;
  unsigned short* ao = (unsigned short*)w; w += (size_t)BATCH * NHEAD * NSEQ * HDIM * 2;
  unsigned short* mid = qb;  // [MROWS, FFD] bf16 aliases qb..ao span (42MB)
  unsigned short* vT = (unsigned short*)w;
  const size_t vT_bytes = (size_t)BATCH * NHEAD * HDIM * KPAD * 2;
  w += vT_bytes;

  size_t used = (size_t)(w - (char*)d_ws);
  size_t all_w_bytes = (NLAYER * (SZ_QKV + SZ_OUT + SZ_FC1 + SZ_FC2) + SZ_DEP) * 2;
  bool upfront = ws_size >= used + all_w_bytes;

  unsigned short *wq_all, *wo_all, *w1_all, *w2_all, *wd;
  if (upfront) {
    wq_all = (unsigned short*)w; w += NLAYER * SZ_QKV * 2;
    wo_all = (unsigned short*)w; w += NLAYER * SZ_OUT * 2;
    w1_all = (unsigned short*)w; w += NLAYER * SZ_FC1 * 2;
    w2_all = (unsigned short*)w; w += NLAYER * SZ_FC2 * 2;
    wd     = (unsigned short*)w; w += SZ_DEP * 2;
    cvt_kernel<<<dim3((NLAYER * SZ_QKV) / 1024), 256, 0, stream>>>(qkv_w, wq_all, NLAYER * SZ_QKV);
    cvt_kernel<<<dim3((NLAYER * SZ_OUT) / 1024), 256, 0, stream>>>(out_w, wo_all, NLAYER * SZ_OUT);
    cvt_kernel<<<dim3((NLAYER * SZ_FC1) / 1024), 256, 0, stream>>>(fc1_w, w1_all, NLAYER * SZ_FC1);
    cvt_kernel<<<dim3((NLAYER * SZ_FC2) / 1024), 256, 0, stream>>>(fc2_w, w2_all, NLAYER * SZ_FC2);
    cvt_kernel<<<dim3(SZ_DEP / 1024), 256, 0, stream>>>(dep_w, wd, SZ_DEP);
  } else {
    wq_all = (unsigned short*)w; w += SZ_QKV * 2;
    wo_all = (unsigned short*)w; w += SZ_OUT * 2;
    w1_all = (unsigned short*)w; w += SZ_FC1 * 2;
    w2_all = (unsigned short*)w; w += SZ_FC2 * 2;
    wd     = (unsigned short*)w; w += SZ_DEP * 2;
    cvt_kernel<<<dim3(SZ_DEP / 1024), 256, 0, stream>>>(dep_w, wd, SZ_DEP);
  }

  // zero vT once per call: guarantees pad columns [NSEQ, KPAD) are 0 for all
  // layers (QKV epilogue only writes columns [0, NSEQ)). Graph-capturable.
  hipMemsetAsync(vT, 0, vT_bytes, stream);

  embed_kernel<<<dim3(MROWS), 128, 0, stream>>>(tok, emb, pe, xb);

  const int lnBlocks = (MROWS + 3) / 4;
  for (int l = 0; l < NLAYER; ++l) {
    unsigned short *wq, *wo, *w1, *w2;
    if (upfront) {
      wq = wq_all + l * SZ_QKV; wo = wo_all + l * SZ_OUT;
      w1 = w1_all + l * SZ_FC1; w2 = w2_all + l * SZ_FC2;
    } else {
      wq = wq_all; wo = wo_all; w1 = w1_all; w2 = w2_all;
      cvt_kernel<<<dim3(SZ_QKV / 1024), 256, 0, stream>>>(qkv_w + l * SZ_QKV, wq, SZ_QKV);
      cvt_kernel<<<dim3(SZ_OUT / 1024), 256, 0, stream>>>(out_w + l * SZ_OUT, wo, SZ_OUT);
      cvt_kernel<<<dim3(SZ_FC1 / 1024), 256, 0, stream>>>(fc1_w + l * SZ_FC1, w1, SZ_FC1);
      cvt_kernel<<<dim3(SZ_FC2 / 1024), 256, 0, stream>>>(fc2_w + l * SZ_FC2, w2, SZ_FC2);
    }

    gemm_bt8<EPI_QKV><<<dim3(41 * 12), 512, 0, stream>>>(
        xb, wq, qkv_b + l * 1536, nullptr, qb, kb, vT, MROWS, 1536, 512);
    attn_kernel<<<dim3(11 * 128), 256, 0, stream>>>(qb, kb, vT, ao);
    gemm_bt<EPI_RESID, 64><<<dim3(4 * 161), 256, 0, stream>>>(
        ao, wo, out_b + l * 512, xb, sb, nullptr, nullptr, MROWS, 512, 512);
    ln_kernel<<<dim3(lnBlocks), 256, 0, stream>>>(sb, ln1_g + l * 512, ln1_b + l * 512, xb, MROWS);
    gemm_bt<EPI_GELU, 128><<<dim3(16 * 81), 256, 0, stream>>>(
        xb, w1, fc1_b + l * 2048, nullptr, mid, nullptr, nullptr, MROWS, 2048, 512);
    gemm_bt<EPI_RESID, 64><<<dim3(4 * 161), 256, 0, stream>>>(
        mid, w2, fc2_b + l * 512, xb, sb, nullptr, nullptr, MROWS, 512, 2048);
    ln_kernel<<<dim3(lnBlocks), 256, 0, stream>>>(sb, ln2_g + l * 512, ln2_b + l * 512, xb, MROWS);
  }

  ln_kernel<<<dim3(lnBlocks), 256, 0, stream>>>(xb, lnf_g, lnf_b, xb, MROWS);
  gemm_bt<EPI_F32OUT, 64><<<dim3(8 * 161), 256, 0, stream>>>(
      xb, wd, dep_b, nullptr, d_out, nullptr, nullptr, MROWS, VOCAB, 512);
}

// Round 17
// 1276.127 us; speedup vs baseline: 1.0314x; 1.0314x over previous
//
#include <hip/hip_runtime.h>
#include <stdint.h>

#define NSEQ 641
#define BATCH 16
#define MROWS (BATCH * NSEQ)   // 10256
#define HID 512
#define FFD 2048
#define NHEAD 8
#define HDIM 64
#define NLAYER 6
#define VOCAB 1024
#define KPAD 704               // padded key length for vT rows (mult of 64)

typedef __bf16 bf16x8 __attribute__((ext_vector_type(8)));
typedef float  f32x4  __attribute__((ext_vector_type(4)));
typedef int    i32x4  __attribute__((ext_vector_type(4)));
typedef short  s16x8  __attribute__((ext_vector_type(8)));
typedef short  s16x4  __attribute__((ext_vector_type(4)));

#define EXP_C 0.18033688011112042f   // 0.125 * log2(e)

// XOR swizzle, 128B row pitch (attn K/V/P tiles). Involution.
__device__ __forceinline__ uint32_t swz(uint32_t b) { return b ^ (((b >> 7) & 7u) << 4); }
// XOR swizzle, 64B row pitch (gemm BK=32 tiles). Involution.
__device__ __forceinline__ uint32_t swz32(uint32_t b) { return b ^ (((b >> 7) & 3u) << 4); }

// XCD-chunked bijective block swizzle.
__device__ __forceinline__ int xcd_swz(int bid, int nwg) {
  int x = bid & 7, j = bid >> 3;
  int q = nwg >> 3, r = nwg & 7;
  return x * q + (x < r ? x : r) + j;
}

__device__ __forceinline__ unsigned short f2bf(float f) {
  uint32_t u = __builtin_bit_cast(uint32_t, f);
  u += 0x7FFFu + ((u >> 16) & 1u);
  return (unsigned short)(u >> 16);
}

__device__ __forceinline__ float bf2f(unsigned short u) {
  uint32_t t = ((uint32_t)u) << 16;
  return __builtin_bit_cast(float, t);
}

__device__ __forceinline__ void gload16(const void* g, void* l) {
  __builtin_amdgcn_global_load_lds(
      (const __attribute__((address_space(1))) uint32_t*)g,
      (__attribute__((address_space(3))) uint32_t*)l, 16, 0, 0);
}

__device__ __forceinline__ bf16x8 ld_lds16(const void* p) {
  return __builtin_bit_cast(bf16x8, *(const i32x4*)p);
}

// ---------------------------------------------------------------------------
// f32 -> bf16 conversion (weights)
// ---------------------------------------------------------------------------
__global__ void cvt_kernel(const float* __restrict__ in,
                           unsigned short* __restrict__ out, int n) {
  int i = (blockIdx.x * 256 + threadIdx.x) * 4;
  if (i >= n) return;
  f32x4 v = *(const f32x4*)(in + i);
  s16x4 o;
  o[0] = (short)f2bf(v[0]); o[1] = (short)f2bf(v[1]);
  o[2] = (short)f2bf(v[2]); o[3] = (short)f2bf(v[3]);
  *(s16x4*)(out + i) = o;
}

// ---------------------------------------------------------------------------
// Embedding: xb = bf16(emb[tok] + pe[n])
// ---------------------------------------------------------------------------
__global__ void embed_kernel(const int* __restrict__ tok,
                             const float* __restrict__ emb,
                             const float* __restrict__ pe,
                             unsigned short* __restrict__ xb) {
  int m = blockIdx.x;
  int n = m % NSEQ;
  int t = tok[m];
  int h = threadIdx.x * 4;
  f32x4 e = *(const f32x4*)(emb + (size_t)t * HID + h);
  f32x4 p = *(const f32x4*)(pe + (size_t)n * HID + h);
  f32x4 v = e + p;
  s16x4 o;
  o[0] = (short)f2bf(v[0]); o[1] = (short)f2bf(v[1]);
  o[2] = (short)f2bf(v[2]); o[3] = (short)f2bf(v[3]);
  *(s16x4*)(xb + (size_t)m * HID + h) = o;
}

// ---------------------------------------------------------------------------
// LayerNorm over H=512, bf16 in -> bf16 out, one wave per row (f32 math).
// ---------------------------------------------------------------------------
__global__ __launch_bounds__(256) void ln_kernel(
    const unsigned short* __restrict__ in, const float* __restrict__ gg,
    const float* __restrict__ bb, unsigned short* __restrict__ out, int rows) {
  int row = blockIdx.x * 4 + (threadIdx.x >> 6);
  if (row >= rows) return;
  int lane = threadIdx.x & 63;
  s16x8 raw = *(const s16x8*)(in + (size_t)row * HID + lane * 8);
  float a[8];
#pragma unroll
  for (int j = 0; j < 8; ++j) a[j] = bf2f((unsigned short)raw[j]);
  float s = a[0] + a[1] + a[2] + a[3] + a[4] + a[5] + a[6] + a[7];
#pragma unroll
  for (int o = 32; o; o >>= 1) s += __shfl_xor(s, o);
  float mean = s * (1.0f / HID);
  float vs = 0.f;
#pragma unroll
  for (int j = 0; j < 8; ++j) { float d = a[j] - mean; vs += d * d; }
#pragma unroll
  for (int o = 32; o; o >>= 1) vs += __shfl_xor(vs, o);
  float rstd = rsqrtf(vs * (1.0f / HID) + 1e-5f);
  f32x4 g0 = *(const f32x4*)(gg + lane * 8);
  f32x4 g1 = *(const f32x4*)(gg + lane * 8 + 4);
  f32x4 b0 = *(const f32x4*)(bb + lane * 8);
  f32x4 b1 = *(const f32x4*)(bb + lane * 8 + 4);
  s16x8 ob;
#pragma unroll
  for (int j = 0; j < 4; ++j) {
    ob[j]     = (short)f2bf((a[j]     - mean) * rstd * g0[j] + b0[j]);
    ob[j + 4] = (short)f2bf((a[j + 4] - mean) * rstd * g1[j] + b1[j]);
  }
  *(s16x8*)(out + (size_t)row * HID + lane * 8) = ob;
}

// ---------------------------------------------------------------------------
// V transpose: vb [bh][NSEQ][64] -> vT [bh][64][KPAD], zero-padded keys.
// ---------------------------------------------------------------------------
__global__ __launch_bounds__(256) void vtrans_kernel(
    const unsigned short* __restrict__ V, unsigned short* __restrict__ vT) {
  const int kt = blockIdx.x;      // 0..10
  const int bh = blockIdx.y;      // 0..127
  const int k0 = kt * 64;
  const int tid = threadIdx.x;
  __shared__ unsigned short lds[64][68];
  const size_t src = (size_t)bh * (NSEQ * HDIM);
#pragma unroll
  for (int it = 0; it < 2; ++it) {
    int k = it * 32 + (tid >> 3);
    int d0 = (tid & 7) * 8;
    int kr = k0 + k;
    s16x8 v = {};
    if (kr < NSEQ) v = *(const s16x8*)(V + src + (size_t)kr * HDIM + d0);
    *(s16x8*)&lds[k][d0] = v;
  }
  __syncthreads();
  const int d = tid & 63;
  const int w = tid >> 6;
  const size_t dst = ((size_t)bh * 64 + d) * KPAD + k0;
#pragma unroll
  for (int it = 0; it < 2; ++it) {
    int kc = w + it * 4;
    s16x8 o;
#pragma unroll
    for (int i = 0; i < 8; ++i) o[i] = lds[kc * 8 + i][d];
    *(s16x8*)(vT + dst + kc * 8) = o;
  }
}

// ---------------------------------------------------------------------------
// GEMM epilogue selector
// ---------------------------------------------------------------------------
enum { EPI_QKV = 0, EPI_GELU = 1, EPI_RESID = 2, EPI_F32OUT = 3 };

template <int EPI>
__device__ __forceinline__ void gemm_epilogue_elem(
    float v, int m, int c, int N,
    const unsigned short* resid, void* out0, void* out1, void* out2) {
  if (EPI == EPI_QKV) {
    int bbq = m / NSEQ, nn = m - bbq * NSEQ;
    int which = c >> 9, hh = (c >> 6) & 7, d = c & 63;
    unsigned short* dst = which == 0 ? (unsigned short*)out0
                        : which == 1 ? (unsigned short*)out1
                                     : (unsigned short*)out2;
    dst[(((size_t)bbq * NHEAD + hh) * NSEQ + nn) * HDIM + d] = f2bf(v);
  } else if (EPI == EPI_GELU) {
    v = 0.5f * v * (1.0f + erff(v * 0.70710678118654752f));
    ((unsigned short*)out0)[(size_t)m * N + c] = f2bf(v);
  } else if (EPI == EPI_RESID) {
    ((unsigned short*)out0)[(size_t)m * N + c] =
        f2bf(v + bf2f(resid[(size_t)m * N + c]));
  } else {
    ((float*)out0)[(size_t)m * N + c] = v;
  }
}

// ---------------------------------------------------------------------------
// GEMM (4-wave): BM x 128 tile, BK=32, 3-deep pipeline, counted vmcnt.
// ---------------------------------------------------------------------------
template <int EPI, int BM>
__global__ __launch_bounds__(256, 3) void gemm_bt(
    const unsigned short* __restrict__ A, const unsigned short* __restrict__ W,
    const float* __restrict__ bias, const unsigned short* __restrict__ resid,
    void* __restrict__ out0, void* __restrict__ out1, void* __restrict__ out2,
    int M, int N, int K) {
  constexpr int ASZ = BM * 64;
  constexpr int BUF = ASZ + 8192;
  constexpr int MI = BM >> 5;
  constexpr int WROWS = BM >> 1;
  constexpr int ALOADS = ASZ / 4096;
  __shared__ char sm[3][BUF];
  const int tid = threadIdx.x, lane = tid & 63, wid = tid >> 6;
  const int wr = wid >> 1, wc = wid & 1;
  const int lg = lane >> 4, lc = lane & 15;

  const int nx = N >> 7;
  const int logical = xcd_swz(blockIdx.x, gridDim.x);
  const int m0 = (logical / nx) * BM, n0 = (logical % nx) * 128;

  f32x4 acc[MI][4] = {};

  auto stage = [&](int kt, char* dst) {
#pragma unroll
    for (int i = 0; i < ALOADS; ++i) {
      uint32_t P = (uint32_t)tid * 16 + i * 4096;
      uint32_t L = swz32(P);
      int row = (int)(L >> 6);
      uint32_t kb = L & 63u;
      int ma = m0 + row; if (ma >= M) ma = M - 1;
      gload16((const char*)A + ((size_t)ma * K + kt) * 2 + kb, dst + P);
    }
#pragma unroll
    for (int i = 0; i < 2; ++i) {
      uint32_t P = (uint32_t)tid * 16 + i * 4096;
      uint32_t L = swz32(P);
      int row = (int)(L >> 6);
      uint32_t kb = L & 63u;
      gload16((const char*)W + ((size_t)(n0 + row) * K + kt) * 2 + kb,
              dst + ASZ + P);
    }
  };

  const int nk = K >> 5;
  stage(0, sm[0]);
  stage(32, sm[1]);

  int bc = 0;
  for (int t = 0; t < nk; ++t) {
    if (t + 1 < nk) {
      if constexpr (ALOADS == 2) asm volatile("s_waitcnt vmcnt(4)" ::: "memory");
      else                       asm volatile("s_waitcnt vmcnt(3)" ::: "memory");
    } else {
      asm volatile("s_waitcnt vmcnt(0)" ::: "memory");
    }
    __builtin_amdgcn_sched_barrier(0);
    __builtin_amdgcn_s_barrier();
    __builtin_amdgcn_sched_barrier(0);
    if (t + 2 < nk) {
      int b2 = bc + 2; if (b2 >= 3) b2 -= 3;
      stage((t + 2) << 5, sm[b2]);
    }
    const char* buf = sm[bc];
    bf16x8 af[MI], bfr[4];
#pragma unroll
    for (int mi = 0; mi < MI; ++mi) {
      int row = wr * WROWS + mi * 16 + lc;
      af[mi] = ld_lds16(buf + swz32((uint32_t)row * 64 + (lg << 4)));
    }
#pragma unroll
    for (int ni = 0; ni < 4; ++ni) {
      int row = wc * 64 + ni * 16 + lc;
      bfr[ni] = ld_lds16(buf + ASZ + swz32((uint32_t)row * 64 + (lg << 4)));
    }
#pragma unroll
    for (int mi = 0; mi < MI; ++mi)
#pragma unroll
      for (int ni = 0; ni < 4; ++ni)
        acc[mi][ni] = __builtin_amdgcn_mfma_f32_16x16x32_bf16(af[mi], bfr[ni], acc[mi][ni], 0, 0, 0);
    asm volatile("s_waitcnt lgkmcnt(0)" ::: "memory");
    __builtin_amdgcn_sched_barrier(0);
    if (++bc == 3) bc = 0;
  }

#pragma unroll
  for (int mi = 0; mi < MI; ++mi) {
#pragma unroll
    for (int g = 0; g < 4; ++g) {
      int m = m0 + wr * WROWS + mi * 16 + lg * 4 + g;
      if (m >= M) continue;
#pragma unroll
      for (int ni = 0; ni < 4; ++ni) {
        int c = n0 + wc * 64 + ni * 16 + lc;
        float v = acc[mi][ni][g] + bias[c];
        gemm_epilogue_elem<EPI>(v, m, c, N, resid, out0, out1, out2);
      }
    }
  }
}

// ---------------------------------------------------------------------------
// GEMM (8-wave): 256x128 tile, 512 threads, BK=32, 2-buffer depth-1.
// Kept ONLY for QKV (the measured R12 win on its 12-wide grid).
// ---------------------------------------------------------------------------
template <int EPI>
__global__ __launch_bounds__(512, 3) void gemm_bt8(
    const unsigned short* __restrict__ A, const unsigned short* __restrict__ W,
    const float* __restrict__ bias, const unsigned short* __restrict__ resid,
    void* __restrict__ out0, void* __restrict__ out1, void* __restrict__ out2,
    int M, int N, int K) {
  __shared__ char sm[2][24576];   // A 256x32 bf16 =16KB | B 128x32 bf16 =8KB
  const int tid = threadIdx.x, lane = tid & 63, wid = tid >> 6;
  const int wr = wid >> 1, wc = wid & 1;        // 4 x 2 waves
  const int lg = lane >> 4, lc = lane & 15;

  const int nx = N >> 7;
  const int logical = xcd_swz(blockIdx.x, gridDim.x);
  const int m0 = (logical / nx) * 256, n0 = (logical % nx) * 128;

  f32x4 acc[4][4] = {};

  auto stage = [&](int kt, char* dst) {
#pragma unroll
    for (int i = 0; i < 2; ++i) {
      uint32_t P = (uint32_t)tid * 16 + i * 8192;
      uint32_t L = swz32(P);
      int row = (int)(L >> 6);
      uint32_t kb = L & 63u;
      int ma = m0 + row; if (ma >= M) ma = M - 1;
      gload16((const char*)A + ((size_t)ma * K + kt) * 2 + kb, dst + P);
    }
    {
      uint32_t P = (uint32_t)tid * 16;
      uint32_t L = swz32(P);
      int row = (int)(L >> 6);
      uint32_t kb = L & 63u;
      gload16((const char*)W + ((size_t)(n0 + row) * K + kt) * 2 + kb,
              dst + 16384 + P);
    }
  };

  const int nk = K >> 5;
  stage(0, sm[0]);

  for (int t = 0; t < nk; ++t) {
    asm volatile("s_waitcnt vmcnt(0)" ::: "memory");
    __builtin_amdgcn_sched_barrier(0);
    __builtin_amdgcn_s_barrier();
    __builtin_amdgcn_sched_barrier(0);
    if (t + 1 < nk) stage((t + 1) << 5, sm[(t + 1) & 1]);
    const char* buf = sm[t & 1];
    bf16x8 af[4], bfr[4];
#pragma unroll
    for (int mi = 0; mi < 4; ++mi) {
      int row = wr * 64 + mi * 16 + lc;
      af[mi] = ld_lds16(buf + swz32((uint32_t)row * 64 + (lg << 4)));
    }
#pragma unroll
    for (int ni = 0; ni < 4; ++ni) {
      int row = wc * 64 + ni * 16 + lc;
      bfr[ni] = ld_lds16(buf + 16384 + swz32((uint32_t)row * 64 + (lg << 4)));
    }
#pragma unroll
    for (int mi = 0; mi < 4; ++mi)
#pragma unroll
      for (int ni = 0; ni < 4; ++ni)
        acc[mi][ni] = __builtin_amdgcn_mfma_f32_16x16x32_bf16(af[mi], bfr[ni], acc[mi][ni], 0, 0, 0);
    asm volatile("s_waitcnt lgkmcnt(0)" ::: "memory");
    __builtin_amdgcn_sched_barrier(0);
  }

#pragma unroll
  for (int mi = 0; mi < 4; ++mi) {
#pragma unroll
    for (int g = 0; g < 4; ++g) {
      int m = m0 + wr * 64 + mi * 16 + lg * 4 + g;
      if (m >= M) continue;
#pragma unroll
      for (int ni = 0; ni < 4; ++ni) {
        int c = n0 + wc * 64 + ni * 16 + lc;
        float v = acc[mi][ni][g] + bias[c];
        gemm_epilogue_elem<EPI>(v, m, c, N, resid, out0, out1, out2);
      }
    }
  }
}

// ---------------------------------------------------------------------------
// Flash attention (R15, best measured): 64-row q-tiles, no-max softmax,
// gload16 double-buffered K/V staging, 40KB LDS -> 4 blocks/CU, provable
// lookahead-tile skip (nkt = qt+1 except qt in {1,6}).
// ---------------------------------------------------------------------------
__global__ __launch_bounds__(256, 4) void attn_kernel(
    const unsigned short* __restrict__ Q, const unsigned short* __restrict__ Kb,
    const unsigned short* __restrict__ vT, unsigned short* __restrict__ O) {
  const int logical = xcd_swz(blockIdx.x, gridDim.x);
  const int qt = logical % 11, bh = logical / 11;
  const int b = bh >> 3, h = bh & 7;
  const int q0 = qt * 64;
  const int tid = threadIdx.x, lane = tid & 63, w = tid >> 6;
  const int lg = lane >> 4, lc = lane & 15;
  __shared__ char smem[40960];  // sK[2][8192] | sV[2][8192] | sP[4][2048]

  const size_t base = (size_t)bh * (NSEQ * HDIM);
  const size_t baseT = (size_t)bh * (HDIM * KPAD);

  bf16x8 qf[2];
  {
    int qr = q0 + w * 16 + lc;
    if (qr > NSEQ - 1) qr = NSEQ - 1;
#pragma unroll
    for (int kk = 0; kk < 2; ++kk)
      qf[kk] = __builtin_bit_cast(
          bf16x8, *(const i32x4*)(Q + base + (size_t)qr * HDIM + kk * 32 + (lg << 3)));
  }

  f32x4 acc[4] = {};
  float lsum[4] = {0.f, 0.f, 0.f, 0.f};
  const int qrow_base = q0 + w * 16 + (lg << 2);

  int nkt = qt + 1 + ((qt == 1 || qt == 6) ? 1 : 0);
  if (nkt > 11) nkt = 11;

  auto stage = [&](int kt, int bufi) {
    const int k0 = kt * 64;
#pragma unroll
    for (int i = 0; i < 2; ++i) {
      uint32_t P = w * 2048 + i * 1024 + lane * 16;
      uint32_t L = swz(P);
      int row = (int)(L >> 7);
      uint32_t kbyte = L & 127u;
      int kr = k0 + row; if (kr > NSEQ - 1) kr = NSEQ - 1;
      gload16((const char*)(Kb + base + (size_t)kr * HDIM) + kbyte,
              smem + bufi * 8192 + w * 2048 + i * 1024);
      gload16((const char*)(vT + baseT + (size_t)row * KPAD + k0) + kbyte,
              smem + 16384 + bufi * 8192 + w * 2048 + i * 1024);
    }
  };

  stage(0, 0);
  __syncthreads();

  for (int kt = 0; kt < nkt; ++kt) {
    if (kt + 1 < nkt) stage(kt + 1, (kt + 1) & 1);
    const char* bK = smem + (kt & 1) * 8192;
    const char* bV = smem + 16384 + (kt & 1) * 8192;
    char* sPw = smem + 32768 + w * 2048;
    const int k0 = kt * 64;

    f32x4 s[4] = {};
#pragma unroll
    for (int nt = 0; nt < 4; ++nt) {
#pragma unroll
      for (int kk = 0; kk < 2; ++kk) {
        int row = nt * 16 + lc;
        bf16x8 kf = ld_lds16(bK + swz((uint32_t)row * 128 + kk * 64 + (lg << 4)));
        s[nt] = __builtin_amdgcn_mfma_f32_16x16x32_bf16(qf[kk], kf, s[nt], 0, 0, 0);
      }
    }

    if (kt < qt) {
#pragma unroll
      for (int g = 0; g < 4; ++g)
#pragma unroll
        for (int nt = 0; nt < 4; ++nt) {
          float p = exp2f(s[nt][g] * EXP_C);
          s[nt][g] = p;
          lsum[g] += p;
        }
    } else if (kt == qt) {
#pragma unroll
      for (int g = 0; g < 4; ++g) {
        int q = qrow_base + g;
        int pp = q / 40;
        int lo = pp * 40 + 1, hi = pp * 40 + 8;
#pragma unroll
        for (int nt = 0; nt < 4; ++nt) {
          int k = k0 + nt * 16 + lc;
          bool ok = ((k <= q) || (k >= lo && k <= hi)) && (k < NSEQ);
          float p = ok ? exp2f(s[nt][g] * EXP_C) : 0.f;
          s[nt][g] = p;
          lsum[g] += p;
        }
      }
    } else {
#pragma unroll
      for (int g = 0; g < 4; ++g) {
        int q = qrow_base + g;
        int pp = q / 40;
        int lo = pp * 40 + 1, hi = pp * 40 + 8;
#pragma unroll
        for (int nt = 0; nt < 4; ++nt) {
          int k = k0 + nt * 16 + lc;
          bool ok = (k >= lo && k <= hi) && (k < NSEQ);
          float p = ok ? exp2f(s[nt][g] * EXP_C) : 0.f;
          s[nt][g] = p;
          lsum[g] += p;
        }
      }
    }

#pragma unroll
    for (int g = 0; g < 4; ++g) {
      int row = (lg << 2) + g;
#pragma unroll
      for (int nt = 0; nt < 4; ++nt) {
        int col = nt * 16 + lc;
        *(short*)(sPw + swz((uint32_t)row * 128 + col * 2)) = (short)f2bf(s[nt][g]);
      }
    }
#pragma unroll
    for (int kk = 0; kk < 2; ++kk) {
      bf16x8 pa = ld_lds16(sPw + swz((uint32_t)lc * 128 + kk * 64 + (lg << 4)));
#pragma unroll
      for (int nt = 0; nt < 4; ++nt) {
        int rowv = nt * 16 + lc;
        bf16x8 vf = ld_lds16(bV + swz((uint32_t)rowv * 128 + kk * 64 + (lg << 4)));
        acc[nt] = __builtin_amdgcn_mfma_f32_16x16x32_bf16(pa, vf, acc[nt], 0, 0, 0);
      }
    }
    __syncthreads();
  }

#pragma unroll
  for (int o = 1; o < 16; o <<= 1)
#pragma unroll
    for (int g = 0; g < 4; ++g) lsum[g] += __shfl_xor(lsum[g], o);

#pragma unroll
  for (int g = 0; g < 4; ++g) {
    int q = qrow_base + g;
    if (q >= NSEQ) continue;
    float inv = 1.0f / lsum[g];
#pragma unroll
    for (int nt = 0; nt < 4; ++nt) {
      int d = nt * 16 + lc;
      O[((size_t)b * NSEQ + q) * HID + h * HDIM + d] = f2bf(acc[nt][g] * inv);
    }
  }
}

// ---------------------------------------------------------------------------
extern "C" void kernel_launch(void* const* d_in, const int* in_sizes, int n_in,
                              void* d_out, int out_size, void* d_ws, size_t ws_size,
                              hipStream_t stream) {
  const int*   tok   = (const int*)d_in[0];
  const float* pe    = (const float*)d_in[2];
  const float* emb   = (const float*)d_in[3];
  const float* qkv_w = (const float*)d_in[4];
  const float* qkv_b = (const float*)d_in[5];
  const float* out_w = (const float*)d_in[6];
  const float* out_b = (const float*)d_in[7];
  const float* ln1_g = (const float*)d_in[8];
  const float* ln1_b = (const float*)d_in[9];
  const float* fc1_w = (const float*)d_in[10];
  const float* fc1_b = (const float*)d_in[11];
  const float* fc2_w = (const float*)d_in[12];
  const float* fc2_b = (const float*)d_in[13];
  const float* ln2_g = (const float*)d_in[14];
  const float* ln2_b = (const float*)d_in[15];
  const float* lnf_g = (const float*)d_in[16];
  const float* lnf_b = (const float*)d_in[17];
  const float* dep_w = (const float*)d_in[18];
  const float* dep_b = (const float*)d_in[19];

  const size_t SZ_QKV = (size_t)1536 * 512;
  const size_t SZ_OUT = (size_t)512 * 512;
  const size_t SZ_FC1 = (size_t)2048 * 512;
  const size_t SZ_FC2 = (size_t)512 * 2048;
  const size_t SZ_DEP = (size_t)VOCAB * 512;

  char* w = (char*)d_ws;
  unsigned short* xb = (unsigned short*)w; w += (size_t)MROWS * HID * 2;
  unsigned short* sb = (unsigned short*)w; w += (size_t)MROWS * HID * 2;
  unsigned short* qb = (unsigned short*)w; w += (size_t)BATCH * NHEAD * NSEQ * HDIM * 2;
  unsigned short* kb = (unsigned short*)w; w += (size_t)BATCH * NHEAD * NSEQ * HDIM * 2;
  unsigned short* vb = (unsigned short*)w; w += (size_t)BATCH * NHEAD * NSEQ * HDIM * 2;
  unsigned short* ao = (unsigned short*)w; w += (size_t)BATCH * NHEAD * NSEQ * HDIM * 2;
  unsigned short* mid = qb;  // [MROWS, FFD] bf16 aliases q/k/v/ao
  unsigned short* vT = (unsigned short*)w; w += (size_t)BATCH * NHEAD * HDIM * KPAD * 2;

  size_t used = (size_t)(w - (char*)d_ws);
  size_t all_w_bytes = (NLAYER * (SZ_QKV + SZ_OUT + SZ_FC1 + SZ_FC2) + SZ_DEP) * 2;
  bool upfront = ws_size >= used + all_w_bytes;

  unsigned short *wq_all, *wo_all, *w1_all, *w2_all, *wd;
  if (upfront) {
    wq_all = (unsigned short*)w; w += NLAYER * SZ_QKV * 2;
    wo_all = (unsigned short*)w; w += NLAYER * SZ_OUT * 2;
    w1_all = (unsigned short*)w; w += NLAYER * SZ_FC1 * 2;
    w2_all = (unsigned short*)w; w += NLAYER * SZ_FC2 * 2;
    wd     = (unsigned short*)w; w += SZ_DEP * 2;
    cvt_kernel<<<dim3((NLAYER * SZ_QKV) / 1024), 256, 0, stream>>>(qkv_w, wq_all, NLAYER * SZ_QKV);
    cvt_kernel<<<dim3((NLAYER * SZ_OUT) / 1024), 256, 0, stream>>>(out_w, wo_all, NLAYER * SZ_OUT);
    cvt_kernel<<<dim3((NLAYER * SZ_FC1) / 1024), 256, 0, stream>>>(fc1_w, w1_all, NLAYER * SZ_FC1);
    cvt_kernel<<<dim3((NLAYER * SZ_FC2) / 1024), 256, 0, stream>>>(fc2_w, w2_all, NLAYER * SZ_FC2);
    cvt_kernel<<<dim3(SZ_DEP / 1024), 256, 0, stream>>>(dep_w, wd, SZ_DEP);
  } else {
    wq_all = (unsigned short*)w; w += SZ_QKV * 2;
    wo_all = (unsigned short*)w; w += SZ_OUT * 2;
    w1_all = (unsigned short*)w; w += SZ_FC1 * 2;
    w2_all = (unsigned short*)w; w += SZ_FC2 * 2;
    wd     = (unsigned short*)w; w += SZ_DEP * 2;
    cvt_kernel<<<dim3(SZ_DEP / 1024), 256, 0, stream>>>(dep_w, wd, SZ_DEP);
  }

  embed_kernel<<<dim3(MROWS), 128, 0, stream>>>(tok, emb, pe, xb);

  const int lnBlocks = (MROWS + 3) / 4;
  for (int l = 0; l < NLAYER; ++l) {
    unsigned short *wq, *wo, *w1, *w2;
    if (upfront) {
      wq = wq_all + l * SZ_QKV; wo = wo_all + l * SZ_OUT;
      w1 = w1_all + l * SZ_FC1; w2 = w2_all + l * SZ_FC2;
    } else {
      wq = wq_all; wo = wo_all; w1 = w1_all; w2 = w2_all;
      cvt_kernel<<<dim3(SZ_QKV / 1024), 256, 0, stream>>>(qkv_w + l * SZ_QKV, wq, SZ_QKV);
      cvt_kernel<<<dim3(SZ_OUT / 1024), 256, 0, stream>>>(out_w + l * SZ_OUT, wo, SZ_OUT);
      cvt_kernel<<<dim3(SZ_FC1 / 1024), 256, 0, stream>>>(fc1_w + l * SZ_FC1, w1, SZ_FC1);
      cvt_kernel<<<dim3(SZ_FC2 / 1024), 256, 0, stream>>>(fc2_w + l * SZ_FC2, w2, SZ_FC2);
    }

    gemm_bt8<EPI_QKV><<<dim3(41 * 12), 512, 0, stream>>>(
        xb, wq, qkv_b + l * 1536, nullptr, qb, kb, vb, MROWS, 1536, 512);
    vtrans_kernel<<<dim3(11, 128), 256, 0, stream>>>(vb, vT);
    attn_kernel<<<dim3(11 * 128), 256, 0, stream>>>(qb, kb, vT, ao);
    gemm_bt<EPI_RESID, 64><<<dim3(4 * 161), 256, 0, stream>>>(
        ao, wo, out_b + l * 512, xb, sb, nullptr, nullptr, MROWS, 512, 512);
    ln_kernel<<<dim3(lnBlocks), 256, 0, stream>>>(sb, ln1_g + l * 512, ln1_b + l * 512, xb, MROWS);
    gemm_bt<EPI_GELU, 128><<<dim3(16 * 81), 256, 0, stream>>>(
        xb, w1, fc1_b + l * 2048, nullptr, mid, nullptr, nullptr, MROWS, 2048, 512);
    gemm_bt<EPI_RESID, 64><<<dim3(4 * 161), 256, 0, stream>>>(
        mid, w2, fc2_b + l * 512, xb, sb, nullptr, nullptr, MROWS, 512, 2048);
    ln_kernel<<<dim3(lnBlocks), 256, 0, stream>>>(sb, ln2_g + l * 512, ln2_b + l * 512, xb, MROWS);
  }

  ln_kernel<<<dim3(lnBlocks), 256, 0, stream>>>(xb, lnf_g, lnf_b, xb, MROWS);
  gemm_bt<EPI_F32OUT, 64><<<dim3(8 * 161), 256, 0, stream>>>(
      xb, wd, dep_b, nullptr, d_out, nullptr, nullptr, MROWS, VOCAB, 512);
}